// Round 1
// baseline (267.118 us; speedup 1.0000x reference)
//
#include <hip/hip_runtime.h>
#include <math.h>

// GenSP: SSN superpixels, x(1,64,384,384), stoken=16.
// nsh=nsw=24 -> S=576 superpixels, 16x16 pixels per block, C=64, P=147456.
// Full label-determining chain in f64 to match the harness's np (f64) reference:
// one wrong argmax paints a wrong superpixel mean (~0.1-0.25 error >> 0.017 thr).

#define NC   64
#define IMH  384
#define IMW  384
#define HWP  (IMH*IMW)      // 147456 pixels
#define NSH  24
#define NSW  24
#define NS   (NSH*NSW)      // 576 superpixels / blocks
#define BSZ  16             // stoken

// ---------------- K1: initial centroids = 16x16 block means (f64) ----------
__global__ __launch_bounds__(256) void k_cent_init(const float* __restrict__ x,
                                                   double* __restrict__ cent) {
    int s = blockIdx.x;
    int by = s / NSW, bx = s % NSW;
    int t = threadIdx.x;
    int w = t >> 6, lane = t & 63;
    __shared__ double part[4][NC];
    int p = w * 64 + lane;                 // pixel within block
    int py = p >> 4, px = p & 15;
    const float* base = x + (size_t)(by * BSZ + py) * IMW + bx * BSZ + px;
    for (int c = 0; c < NC; ++c) {
        double v = (double)base[(size_t)c * HWP];
        #pragma unroll
        for (int off = 32; off >= 1; off >>= 1) v += __shfl_down(v, off, 64);
        if (lane == 0) part[w][c] = v;
    }
    __syncthreads();
    if (t < NC)
        cent[s * NC + t] = (part[0][t] + part[1][t] + part[2][t] + part[3][t]) * (1.0 / 256.0);
}

// ------------- K2: affinity (f64 softmax) + per-block partial sums ---------
// block b: pixels share the same 9 candidate superpixels b+(dy,dx).
// bnum[b][k][c] = sum_p aff[k][p]*x[c][p]   (over this block's 256 pixels)
// bden[b][k]    = sum_p aff[k][p]
__global__ __launch_bounds__(256) void k_iter(const float* __restrict__ x,
                                              const double* __restrict__ cent,
                                              double* __restrict__ bnum,
                                              double* __restrict__ bden) {
    int b = blockIdx.x;
    int by = b / NSW, bx = b % NSW;
    int t = threadIdx.x;
    __shared__ double scent[9][NC];        // 4608 B
    __shared__ float  pxt[256][NC + 1];    // 66560 B, +1 pad -> conflict-free reads
    __shared__ double aff[9][256];         // 18432 B

    for (int idx = t; idx < 9 * NC; idx += 256) {
        int k = idx >> 6, c = idx & 63;
        int cy = by + (k / 3) - 1, cx = bx + (k % 3) - 1;
        scent[k][c] = (cy >= 0 && cy < NSH && cx >= 0 && cx < NSW)
                          ? cent[(cy * NSW + cx) * NC + c] : 0.0;
    }
    bool vld[9];
    #pragma unroll
    for (int k = 0; k < 9; ++k) {
        int cy = by + k / 3 - 1, cx = bx + k % 3 - 1;
        vld[k] = (cy >= 0) && (cy < NSH) && (cx >= 0) && (cx < NSW);
    }
    __syncthreads();

    {
        int p = t;
        int py = p >> 4, px = p & 15;
        const float* base = x + (size_t)(by * BSZ + py) * IMW + bx * BSZ + px;
        double d[9];
        #pragma unroll
        for (int k = 0; k < 9; ++k) d[k] = 0.0;
        for (int c = 0; c < NC; ++c) {
            float vf = base[(size_t)c * HWP];
            pxt[p][c] = vf;
            double v = (double)vf;
            #pragma unroll
            for (int k = 0; k < 9; ++k) {
                double diff = v - scent[k][c];
                d[k] = fma(diff, diff, d[k]);
            }
        }
        double m = -1e300;
        #pragma unroll
        for (int k = 0; k < 9; ++k) if (vld[k]) m = fmax(m, -d[k]);
        double e[9], ssum = 0.0;
        #pragma unroll
        for (int k = 0; k < 9; ++k) { e[k] = vld[k] ? exp(-d[k] - m) : 0.0; ssum += e[k]; }
        #pragma unroll
        for (int k = 0; k < 9; ++k) aff[k][p] = e[k] / ssum;
    }
    __syncthreads();

    // dot phase: wave w owns k = w, w+4, w+8; lane = channel.
    int w = t >> 6, lane = t & 63;
    for (int k = w; k < 9; k += 4) {
        double a0 = 0, a1 = 0, a2 = 0, a3 = 0;
        for (int p2 = 0; p2 < 256; p2 += 4) {
            a0 = fma(aff[k][p2 + 0], (double)pxt[p2 + 0][lane], a0);
            a1 = fma(aff[k][p2 + 1], (double)pxt[p2 + 1][lane], a1);
            a2 = fma(aff[k][p2 + 2], (double)pxt[p2 + 2][lane], a2);
            a3 = fma(aff[k][p2 + 3], (double)pxt[p2 + 3][lane], a3);
        }
        bnum[((size_t)b * 9 + k) * NC + lane] = (a0 + a1) + (a2 + a3);
        double dn = aff[k][lane] + aff[k][lane + 64] + aff[k][lane + 128] + aff[k][lane + 192];
        #pragma unroll
        for (int off = 32; off >= 1; off >>= 1) dn += __shfl_down(dn, off, 64);
        if (lane == 0) bden[b * 9 + k] = dn;
    }
}

// ------- K3: gather per-block partials -> new centroid (num/(den+1e-16)) ---
__global__ __launch_bounds__(64) void k_gather_cent(const double* __restrict__ bnum,
                                                    const double* __restrict__ bden,
                                                    double* __restrict__ cent) {
    int s = blockIdx.x, c = threadIdx.x;
    int sy = s / NSW, sx = s % NSW;
    double num = 0.0, den = 0.0;
    #pragma unroll
    for (int k = 0; k < 9; ++k) {
        int by2 = sy - (k / 3 - 1), bx2 = sx - (k % 3 - 1);
        if (by2 >= 0 && by2 < NSH && bx2 >= 0 && bx2 < NSW) {
            int b = by2 * NSW + bx2;
            num += bnum[((size_t)b * 9 + k) * NC + c];
            den += bden[b * 9 + k];
        }
    }
    cent[s * NC + c] = num / (den + 1e-16);
}

// ---- K4: final pass: argmax label (min f64 distance, first wins) + paint
//      partial sums of x over hard labels (indicator instead of affinity) ----
__global__ __launch_bounds__(256) void k_final(const float* __restrict__ x,
                                               const double* __restrict__ cent,
                                               int* __restrict__ labels,
                                               double* __restrict__ bnum,
                                               double* __restrict__ bden) {
    int b = blockIdx.x;
    int by = b / NSW, bx = b % NSW;
    int t = threadIdx.x;
    __shared__ double scent[9][NC];
    __shared__ float  pxt[256][NC + 1];
    __shared__ float  ind[9][256];

    for (int idx = t; idx < 9 * NC; idx += 256) {
        int k = idx >> 6, c = idx & 63;
        int cy = by + (k / 3) - 1, cx = bx + (k % 3) - 1;
        scent[k][c] = (cy >= 0 && cy < NSH && cx >= 0 && cx < NSW)
                          ? cent[(cy * NSW + cx) * NC + c] : 0.0;
    }
    bool vld[9];
    #pragma unroll
    for (int k = 0; k < 9; ++k) {
        int cy = by + k / 3 - 1, cx = bx + k % 3 - 1;
        vld[k] = (cy >= 0) && (cy < NSH) && (cx >= 0) && (cx < NSW);
    }
    __syncthreads();

    {
        int p = t;
        int py = p >> 4, px = p & 15;
        const float* base = x + (size_t)(by * BSZ + py) * IMW + bx * BSZ + px;
        double d[9];
        #pragma unroll
        for (int k = 0; k < 9; ++k) d[k] = 0.0;
        for (int c = 0; c < NC; ++c) {
            float vf = base[(size_t)c * HWP];
            pxt[p][c] = vf;
            double v = (double)vf;
            #pragma unroll
            for (int k = 0; k < 9; ++k) {
                double diff = v - scent[k][c];
                d[k] = fma(diff, diff, d[k]);
            }
        }
        double bestd = 1e300; int bestk = 0;
        #pragma unroll
        for (int k = 0; k < 9; ++k)
            if (vld[k] && d[k] < bestd) { bestd = d[k]; bestk = k; }   // first-max-wins
        int lab = (by + bestk / 3 - 1) * NSW + (bx + bestk % 3 - 1);
        labels[(size_t)(by * BSZ + py) * IMW + bx * BSZ + px] = lab;
        #pragma unroll
        for (int k = 0; k < 9; ++k) ind[k][p] = (k == bestk) ? 1.0f : 0.0f;
    }
    __syncthreads();

    int w = t >> 6, lane = t & 63;
    for (int k = w; k < 9; k += 4) {
        double a0 = 0, a1 = 0, a2 = 0, a3 = 0;
        for (int p2 = 0; p2 < 256; p2 += 4) {
            a0 = fma((double)ind[k][p2 + 0], (double)pxt[p2 + 0][lane], a0);
            a1 = fma((double)ind[k][p2 + 1], (double)pxt[p2 + 1][lane], a1);
            a2 = fma((double)ind[k][p2 + 2], (double)pxt[p2 + 2][lane], a2);
            a3 = fma((double)ind[k][p2 + 3], (double)pxt[p2 + 3][lane], a3);
        }
        bnum[((size_t)b * 9 + k) * NC + lane] = (a0 + a1) + (a2 + a3);
        double dn = (double)ind[k][lane] + (double)ind[k][lane + 64]
                  + (double)ind[k][lane + 128] + (double)ind[k][lane + 192];
        #pragma unroll
        for (int off = 32; off >= 1; off >>= 1) dn += __shfl_down(dn, off, 64);
        if (lane == 0) bden[b * 9 + k] = dn;
    }
}

// --------- K5: gather paint sums -> per-superpixel channel means (f32) -----
__global__ __launch_bounds__(64) void k_means_(const double* __restrict__ bnum,
                                               const double* __restrict__ bden,
                                               float* __restrict__ means) {
    int s = blockIdx.x, c = threadIdx.x;
    int sy = s / NSW, sx = s % NSW;
    double num = 0.0, den = 0.0;
    #pragma unroll
    for (int k = 0; k < 9; ++k) {
        int by2 = sy - (k / 3 - 1), bx2 = sx - (k % 3 - 1);
        if (by2 >= 0 && by2 < NSH && bx2 >= 0 && bx2 < NSW) {
            int b = by2 * NSW + bx2;
            num += bnum[((size_t)b * 9 + k) * NC + c];
            den += bden[b * 9 + k];
        }
    }
    means[s * NC + c] = (float)(num / fmax(den, 1.0));
}

// ---------------------- K6: paint out[c][p] = means[lab[p]][c] -------------
__global__ __launch_bounds__(256) void k_paint(const int* __restrict__ labels,
                                               const float* __restrict__ means,
                                               float* __restrict__ out) {
    int c = blockIdx.y;
    int p = blockIdx.x * 256 + threadIdx.x;
    out[(size_t)c * HWP + p] = means[labels[p] * NC + c];
}

extern "C" void kernel_launch(void* const* d_in, const int* in_sizes, int n_in,
                              void* d_out, int out_size, void* d_ws, size_t ws_size,
                              hipStream_t stream) {
    const float* x = (const float*)d_in[0];
    float* out = (float*)d_out;
    char* ws = (char*)d_ws;

    constexpr size_t CENT_B  = (size_t)NS * NC * 8;       // 294912
    constexpr size_t LAB_B   = (size_t)HWP * 4;           // 589824
    constexpr size_t MEANS_B = (size_t)NS * NC * 4;       // 147456
    constexpr size_t SMALL   = CENT_B + LAB_B + MEANS_B;  // 1032192
    constexpr size_t BNUM_B  = (size_t)NS * 9 * NC * 8;   // 2654208
    constexpr size_t BDEN_B  = (size_t)NS * 9 * 8;        // 41472

    double* cent   = (double*)ws;
    int*    labels = (int*)(ws + CENT_B);
    float*  means  = (float*)(ws + CENT_B + LAB_B);
    double* bnum;
    double* bden;
    if (ws_size >= SMALL + BNUM_B + BDEN_B) {
        bnum = (double*)(ws + SMALL);
        bden = (double*)(ws + SMALL + BNUM_B);
    } else {
        // fall back: big per-block partials live at the front of d_out;
        // k_paint fully overwrites d_out afterwards (reads only labels/means in ws).
        bnum = (double*)d_out;
        bden = (double*)((char*)d_out + BNUM_B);
    }

    k_cent_init<<<NS, 256, 0, stream>>>(x, cent);
    for (int it = 0; it < 2; ++it) {                      // N_ITER-1 = 2 updates
        k_iter<<<NS, 256, 0, stream>>>(x, cent, bnum, bden);
        k_gather_cent<<<NS, 64, 0, stream>>>(bnum, bden, cent);
    }
    k_final<<<NS, 256, 0, stream>>>(x, cent, labels, bnum, bden);
    k_means_<<<NS, 64, 0, stream>>>(bnum, bden, means);
    k_paint<<<dim3(HWP / 256, NC), 256, 0, stream>>>(labels, means, out);
}

// Round 3
// 180.963 us; speedup vs baseline: 1.4761x; 1.4761x over previous
//
#include <hip/hip_runtime.h>
#include <math.h>

// GenSP: SSN superpixels, x(1,64,384,384), stoken=16.
// S=576 superpixels (24x24 grid of 16x16 blocks), C=64, P=147456, N_ITER=3.
// Label-determining chain kept in f64 (R1 bit-matched the np f64 reference).
// R2: LDS 89.6->52.3KB (3 blocks/CU), vectorized staging, gather folded into
// prologue (ping-pong partials), vectorized paint.

#define NC   64
#define IMW  384
#define HWP  (384*384)
#define NSH  24
#define NSW  24
#define NS   (NSH*NSW)
#define XROW 66          // padded row stride (floats) for staged x chunks

// stage one 64px x 64ch chunk (16 KB) into LDS: 4 float4 loads + 16 ds_writes per thread
__device__ __forceinline__ void stage_chunk(const float* __restrict__ x,
                                            int by, int bx, int g,
                                            float* __restrict__ xb, int t) {
    int q = t >> 2, r = t & 3;   // q = channel, r = px-quad
    const float* gp = x + (size_t)q * HWP + (size_t)(by * 16 + g * 4) * IMW + bx * 16 + r * 4;
    #pragma unroll
    for (int j = 0; j < 4; ++j) {
        float4 v = *(const float4*)(gp + j * IMW);
        int p0 = j * 16 + r * 4;
        xb[(p0 + 0) * XROW + q] = v.x;
        xb[(p0 + 1) * XROW + q] = v.y;
        xb[(p0 + 2) * XROW + q] = v.z;
        xb[(p0 + 3) * XROW + q] = v.w;
    }
}

// ---------------- K1: initial centroids = 16x16 block means (f64) ----------
__global__ __launch_bounds__(256) void k_cent_init(const float* __restrict__ x,
                                                   double* __restrict__ cent) {
    int s = blockIdx.x, by = s / NSW, bx = s % NSW;
    int t = threadIdx.x, c = t >> 2, r = t & 3;
    const float* gp = x + (size_t)c * HWP + (size_t)(by * 16) * IMW + bx * 16;
    double sum = 0.0;
    #pragma unroll
    for (int jr = 0; jr < 4; ++jr) {
        int row = r + jr * 4;
        #pragma unroll
        for (int i = 0; i < 4; ++i) {
            float4 v = *(const float4*)(gp + (size_t)row * IMW + i * 4);
            sum += (double)v.x; sum += (double)v.y; sum += (double)v.z; sum += (double)v.w;
        }
    }
    sum += __shfl_xor(sum, 1, 64);
    sum += __shfl_xor(sum, 2, 64);
    if (r == 0) cent[s * NC + c] = sum * (1.0 / 256.0);
}

// ------------- K2: [gather centroids] + affinity + per-block partials -------
__global__ __launch_bounds__(256, 3) void k_iter(const float* __restrict__ x,
        const double* __restrict__ cent,
        const double* __restrict__ bnumI, const double* __restrict__ bdenI,
        double* __restrict__ bnumO, double* __restrict__ bdenO, int gather) {
    int b = blockIdx.x, by = b / NSW, bx = b % NSW;
    int t = threadIdx.x;
    __shared__ float  xbuf[2][64 * XROW];   // 33792 B
    __shared__ double affbuf[9 * 256];      // 18432 B (scent aliased pre-softmax)
    __shared__ double dred[9];
    double* scent = affbuf;                 // [9][64]

    // ---- prologue: 9 candidate centroids ----
    if (gather) {
        if (t < 9) {
            int cy = by + t / 3 - 1, cx = bx + t % 3 - 1;
            double den = 0.0;
            if (cy >= 0 && cy < NSH && cx >= 0 && cx < NSW) {
                #pragma unroll
                for (int k = 0; k < 9; ++k) {
                    int by2 = cy - (k / 3 - 1), bx2 = cx - (k % 3 - 1);
                    if (by2 >= 0 && by2 < NSH && bx2 >= 0 && bx2 < NSW)
                        den += bdenI[(by2 * NSW + bx2) * 9 + k];
                }
            }
            dred[t] = den + 1e-16;
        }
        __syncthreads();
        for (int idx = t; idx < 576; idx += 256) {
            int j = idx >> 6, c = idx & 63;
            int cy = by + j / 3 - 1, cx = bx + j % 3 - 1;
            double v = 0.0;
            if (cy >= 0 && cy < NSH && cx >= 0 && cx < NSW) {
                double num = 0.0;
                #pragma unroll
                for (int k = 0; k < 9; ++k) {
                    int by2 = cy - (k / 3 - 1), bx2 = cx - (k % 3 - 1);
                    if (by2 >= 0 && by2 < NSH && bx2 >= 0 && bx2 < NSW)
                        num += bnumI[((size_t)(by2 * NSW + bx2) * 9 + k) * NC + c];
                }
                v = num / dred[j];
            }
            scent[j * NC + c] = v;
        }
    } else {
        for (int idx = t; idx < 576; idx += 256) {
            int j = idx >> 6, c = idx & 63;
            int cy = by + j / 3 - 1, cx = bx + j % 3 - 1;
            scent[j * NC + c] = (cy >= 0 && cy < NSH && cx >= 0 && cx < NSW)
                                    ? cent[(cy * NSW + cx) * NC + c] : 0.0;
        }
    }
    __syncthreads();

    bool vld[9];
    #pragma unroll
    for (int k = 0; k < 9; ++k) {
        int cy = by + k / 3 - 1, cx = bx + k % 3 - 1;
        vld[k] = (cy >= 0) && (cy < NSH) && (cx >= 0) && (cx < NSW);
    }

    // ---- distance (global scalar reads, latency hidden by occupancy) ----
    {
        int p = t, py = p >> 4, px = p & 15;
        const float* base = x + (size_t)(by * 16 + py) * IMW + bx * 16 + px;
        double d[9];
        #pragma unroll
        for (int k = 0; k < 9; ++k) d[k] = 0.0;
        for (int c = 0; c < NC; ++c) {
            double v = (double)base[(size_t)c * HWP];
            #pragma unroll
            for (int k = 0; k < 9; ++k) {
                double diff = v - scent[k * NC + c];
                d[k] = fma(diff, diff, d[k]);
            }
        }
        double m = -1e300;
        #pragma unroll
        for (int k = 0; k < 9; ++k) if (vld[k]) m = fmax(m, -d[k]);
        double e[9], ssum = 0.0;
        #pragma unroll
        for (int k = 0; k < 9; ++k) { e[k] = vld[k] ? exp(-d[k] - m) : 0.0; ssum += e[k]; }
        double inv = 1.0 / ssum;
        __syncthreads();                       // all scent reads done -> can clobber
        #pragma unroll
        for (int k = 0; k < 9; ++k) affbuf[k * 256 + p] = e[k] * inv;
    }
    __syncthreads();

    // ---- den per (b,k): same reduce pattern as R1 (bit-identical order) ----
    int w = t >> 6, lane = t & 63;
    #pragma unroll
    for (int s = 0; s < 3; ++s) {
        int k = w + 4 * s;
        if (k < 9) {
            double dn = affbuf[k * 256 + lane] + affbuf[k * 256 + 64 + lane]
                      + affbuf[k * 256 + 128 + lane] + affbuf[k * 256 + 192 + lane];
            #pragma unroll
            for (int off = 32; off >= 1; off >>= 1) dn += __shfl_down(dn, off, 64);
            if (lane == 0) bdenO[b * 9 + k] = dn;
        }
    }

    // ---- dot phase: chunked double-buffered LDS, lane=(p-half, c-pair) ----
    double acc[3][2] = {{0, 0}, {0, 0}, {0, 0}};
    int ph = lane >> 5, cp = lane & 31, c0 = cp * 2;
    stage_chunk(x, by, bx, 0, xbuf[0], t);
    __syncthreads();
    for (int g = 0; g < 4; ++g) {
        const float* xb = xbuf[g & 1];
        if (g < 3) stage_chunk(x, by, bx, g + 1, xbuf[(g + 1) & 1], t);
        for (int p2 = 0; p2 < 32; ++p2) {
            int p = ph * 32 + p2;
            float2 xv = *(const float2*)&xb[p * XROW + c0];
            double x0 = (double)xv.x, x1 = (double)xv.y;
            #pragma unroll
            for (int s = 0; s < 3; ++s) {
                int k = w + 4 * s;
                if (k < 9) {
                    double av = affbuf[k * 256 + g * 64 + p];
                    acc[s][0] = fma(av, x0, acc[s][0]);
                    acc[s][1] = fma(av, x1, acc[s][1]);
                }
            }
        }
        __syncthreads();
    }
    #pragma unroll
    for (int s = 0; s < 3; ++s) {
        double a0 = acc[s][0] + __shfl_down(acc[s][0], 32, 64);
        double a1 = acc[s][1] + __shfl_down(acc[s][1], 32, 64);
        int k = w + 4 * s;
        if (k < 9 && ph == 0) {
            double2 st; st.x = a0; st.y = a1;
            *(double2*)&bnumO[((size_t)b * 9 + k) * NC + c0] = st;
        }
    }
}

// ---- K3: final: gather cent, argmax labels, hard-label partial sums -------
__global__ __launch_bounds__(256, 3) void k_final(const float* __restrict__ x,
        const double* __restrict__ bnumI, const double* __restrict__ bdenI,
        int* __restrict__ labels,
        double* __restrict__ bnumO, double* __restrict__ bdenO) {
    int b = blockIdx.x, by = b / NSW, bx = b % NSW;
    int t = threadIdx.x;
    __shared__ float  xbuf[2][64 * XROW];
    __shared__ double affbuf[9 * 256];
    __shared__ double dred[9];
    double* scent = affbuf;
    int* bestka = (int*)affbuf;             // alias, live after distance

    if (t < 9) {
        int cy = by + t / 3 - 1, cx = bx + t % 3 - 1;
        double den = 0.0;
        if (cy >= 0 && cy < NSH && cx >= 0 && cx < NSW) {
            #pragma unroll
            for (int k = 0; k < 9; ++k) {
                int by2 = cy - (k / 3 - 1), bx2 = cx - (k % 3 - 1);
                if (by2 >= 0 && by2 < NSH && bx2 >= 0 && bx2 < NSW)
                    den += bdenI[(by2 * NSW + bx2) * 9 + k];
            }
        }
        dred[t] = den + 1e-16;
    }
    __syncthreads();
    for (int idx = t; idx < 576; idx += 256) {
        int j = idx >> 6, c = idx & 63;
        int cy = by + j / 3 - 1, cx = bx + j % 3 - 1;
        double v = 0.0;
        if (cy >= 0 && cy < NSH && cx >= 0 && cx < NSW) {
            double num = 0.0;
            #pragma unroll
            for (int k = 0; k < 9; ++k) {
                int by2 = cy - (k / 3 - 1), bx2 = cx - (k % 3 - 1);
                if (by2 >= 0 && by2 < NSH && bx2 >= 0 && bx2 < NSW)
                    num += bnumI[((size_t)(by2 * NSW + bx2) * 9 + k) * NC + c];
            }
            v = num / dred[j];
        }
        scent[j * NC + c] = v;
    }
    __syncthreads();

    bool vld[9];
    #pragma unroll
    for (int k = 0; k < 9; ++k) {
        int cy = by + k / 3 - 1, cx = bx + k % 3 - 1;
        vld[k] = (cy >= 0) && (cy < NSH) && (cx >= 0) && (cx < NSW);
    }

    int bestk = 0;
    {
        int p = t, py = p >> 4, px = p & 15;
        const float* base = x + (size_t)(by * 16 + py) * IMW + bx * 16 + px;
        double d[9];
        #pragma unroll
        for (int k = 0; k < 9; ++k) d[k] = 0.0;
        for (int c = 0; c < NC; ++c) {
            double v = (double)base[(size_t)c * HWP];
            #pragma unroll
            for (int k = 0; k < 9; ++k) {
                double diff = v - scent[k * NC + c];
                d[k] = fma(diff, diff, d[k]);
            }
        }
        double bestd = 1e300;
        #pragma unroll
        for (int k = 0; k < 9; ++k)
            if (vld[k] && d[k] < bestd) { bestd = d[k]; bestk = k; }
        int lab = (by + bestk / 3 - 1) * NSW + (bx + bestk % 3 - 1);
        labels[(size_t)(by * 16 + py) * IMW + bx * 16 + px] = lab;
    }
    __syncthreads();                        // scent dead
    bestka[t] = bestk;
    __syncthreads();

    int w = t >> 6, lane = t & 63;
    #pragma unroll
    for (int s = 0; s < 3; ++s) {
        int k = w + 4 * s;
        if (k < 9) {
            int cnt = (bestka[lane] == k) + (bestka[64 + lane] == k)
                    + (bestka[128 + lane] == k) + (bestka[192 + lane] == k);
            #pragma unroll
            for (int off = 32; off >= 1; off >>= 1) cnt += __shfl_down(cnt, off, 64);
            if (lane == 0) bdenO[b * 9 + k] = (double)cnt;
        }
    }

    double acc[3][2] = {{0, 0}, {0, 0}, {0, 0}};
    int ph = lane >> 5, cp = lane & 31, c0 = cp * 2;
    stage_chunk(x, by, bx, 0, xbuf[0], t);
    __syncthreads();
    for (int g = 0; g < 4; ++g) {
        const float* xb = xbuf[g & 1];
        if (g < 3) stage_chunk(x, by, bx, g + 1, xbuf[(g + 1) & 1], t);
        for (int p2 = 0; p2 < 32; ++p2) {
            int p = ph * 32 + p2;
            int bk = bestka[g * 64 + p];
            float2 xv = *(const float2*)&xb[p * XROW + c0];
            double x0 = (double)xv.x, x1 = (double)xv.y;
            #pragma unroll
            for (int s = 0; s < 3; ++s) {
                int k = w + 4 * s;
                if (k < 9 && bk == k) { acc[s][0] += x0; acc[s][1] += x1; }
            }
        }
        __syncthreads();
    }
    #pragma unroll
    for (int s = 0; s < 3; ++s) {
        double a0 = acc[s][0] + __shfl_down(acc[s][0], 32, 64);
        double a1 = acc[s][1] + __shfl_down(acc[s][1], 32, 64);
        int k = w + 4 * s;
        if (k < 9 && ph == 0) {
            double2 st; st.x = a0; st.y = a1;
            *(double2*)&bnumO[((size_t)b * 9 + k) * NC + c0] = st;
        }
    }
}

// --------- K4: gather paint sums -> per-superpixel channel means (f32) -----
__global__ __launch_bounds__(64) void k_means_(const double* __restrict__ bnum,
                                               const double* __restrict__ bden,
                                               float* __restrict__ means) {
    int s = blockIdx.x, c = threadIdx.x;
    int sy = s / NSW, sx = s % NSW;
    double num = 0.0, den = 0.0;
    #pragma unroll
    for (int k = 0; k < 9; ++k) {
        int by2 = sy - (k / 3 - 1), bx2 = sx - (k % 3 - 1);
        if (by2 >= 0 && by2 < NSH && bx2 >= 0 && bx2 < NSW) {
            int b = by2 * NSW + bx2;
            num += bnum[((size_t)b * 9 + k) * NC + c];
            den += bden[b * 9 + k];
        }
    }
    means[s * NC + c] = (float)(num / fmax(den, 1.0));
}

// ---------------------- K5: paint out[c][p] = means[lab[p]][c] -------------
__global__ __launch_bounds__(256) void k_paint(const int* __restrict__ labels,
                                               const float* __restrict__ means,
                                               float* __restrict__ out) {
    int c = blockIdx.y;
    int p0 = (blockIdx.x * 256 + threadIdx.x) * 4;
    int4 lb = *(const int4*)&labels[p0];
    float4 o;
    o.x = means[lb.x * NC + c];
    o.y = means[lb.y * NC + c];
    o.z = means[lb.z * NC + c];
    o.w = means[lb.w * NC + c];
    *(float4*)&out[(size_t)c * HWP + p0] = o;
}

extern "C" void kernel_launch(void* const* d_in, const int* in_sizes, int n_in,
                              void* d_out, int out_size, void* d_ws, size_t ws_size,
                              hipStream_t stream) {
    const float* x = (const float*)d_in[0];
    float* out = (float*)d_out;
    char* ws = (char*)d_ws;

    constexpr size_t CENT_B  = (size_t)NS * NC * 8;        // 294912
    constexpr size_t LAB_B   = (size_t)HWP * 4;            // 589824
    constexpr size_t MEANS_B = (size_t)NS * NC * 4;        // 147456
    constexpr size_t BNUM_B  = (size_t)NS * 9 * NC * 8;    // 2654208
    constexpr size_t BDEN_B  = (size_t)NS * 9 * 8;         // 41472
    constexpr size_t PP_B    = BNUM_B + BDEN_B;            // one ping-pong set

    // allocation cascade: everything in ws if it fits; else big stuff in d_out
    // (d_out regions are consumed before k_paint overwrites all of d_out).
    char* p_small;   // labels + means (+cent) — must NOT live in d_out (paint reads them)
    double *cent, *bnumA, *bdenA, *bnumB, *bdenB;
    int* labels; float* means;
    size_t need_all = CENT_B + LAB_B + MEANS_B + 2 * PP_B;
    if (ws_size >= need_all) {
        p_small = ws;
        labels = (int*)p_small; means = (float*)(p_small + LAB_B);
        cent = (double*)(p_small + LAB_B + MEANS_B);
        bnumA = (double*)(ws + CENT_B + LAB_B + MEANS_B);
        bdenA = (double*)((char*)bnumA + BNUM_B);
        bnumB = (double*)((char*)bdenA + BDEN_B);
        bdenB = (double*)((char*)bnumB + BNUM_B);
    } else {
        // labels+means (+cent if room) in ws; ping-pong partials in d_out front
        labels = (int*)ws; means = (float*)(ws + LAB_B);
        char* od = (char*)d_out;
        bnumA = (double*)od;                bdenA = (double*)(od + BNUM_B);
        bnumB = (double*)(od + PP_B);       bdenB = (double*)(od + PP_B + BNUM_B);
        if (ws_size >= LAB_B + MEANS_B + CENT_B)
            cent = (double*)(ws + LAB_B + MEANS_B);
        else
            cent = (double*)(od + 2 * PP_B);   // consumed by first k_iter, safe
    }

    k_cent_init<<<NS, 256, 0, stream>>>(x, cent);
    k_iter<<<NS, 256, 0, stream>>>(x, cent, nullptr, nullptr, bnumA, bdenA, 0);
    k_iter<<<NS, 256, 0, stream>>>(x, nullptr, bnumA, bdenA, bnumB, bdenB, 1);
    k_final<<<NS, 256, 0, stream>>>(x, bnumB, bdenB, labels, bnumA, bdenA);
    k_means_<<<NS, 64, 0, stream>>>(bnumA, bdenA, means);
    k_paint<<<dim3(HWP / 1024, NC), 256, 0, stream>>>(labels, means, out);
}

// Round 4
// 174.453 us; speedup vs baseline: 1.5312x; 1.0373x over previous
//
#include <hip/hip_runtime.h>
#include <math.h>

// GenSP: SSN superpixels, x(1,64,384,384), stoken=16.
// S=576 superpixels (24x24 grid of 16x16 px blocks), C=64, P=147456, N_ITER=3.
// f64 label-determining chain (R1/R3 bit-matched np f64 reference, absmax 0.0).
// R4: grid 576 -> 2304 (4 row-chunks of 64px per superpixel block) to fix the
// 2.25-blocks/CU starvation; single LDS staging serves distance AND dot
// (FETCH 73->37MB per kernel); centroid gather/update in tiny side kernels.

#define NC   64
#define IMW  384
#define HWP  (384*384)
#define NSH  24
#define NSW  24
#define NS   (NSH*NSW)
#define NBG  (NS*4)      // 2304 chunk-blocks
#define XROW 66          // padded LDS row stride (floats): 66%32=2 -> <=2-way banks

// ---- K1a: per-chunk partial sums for initial centroids --------------------
__global__ __launch_bounds__(256) void k_cent_part(const float* __restrict__ x,
                                                   double* __restrict__ centp) {
    int bg = blockIdx.x, b = bg >> 2, g = bg & 3;
    int by = b / NSW, bx = b % NSW;
    int t = threadIdx.x, q = t >> 2, r = t & 3;     // q=channel, r=col-quad
    const float* gp = x + (size_t)q * HWP + (size_t)(by * 16 + g * 4) * IMW + bx * 16 + r * 4;
    double s = 0.0;
    #pragma unroll
    for (int j = 0; j < 4; ++j) {                   // 4 rows of the chunk
        float4 v = *(const float4*)(gp + (size_t)j * IMW);
        s += (double)v.x; s += (double)v.y; s += (double)v.z; s += (double)v.w;
    }
    s += __shfl_xor(s, 1, 64);
    s += __shfl_xor(s, 2, 64);
    if (r == 0) centp[(size_t)bg * NC + q] = s;
}

// ---- K1b: reduce 4 chunk partials -> initial cent -------------------------
__global__ __launch_bounds__(64) void k_cent_red(const double* __restrict__ centp,
                                                 double* __restrict__ cent) {
    int s = blockIdx.x, c = threadIdx.x;
    double v = centp[(size_t)(s * 4 + 0) * NC + c] + centp[(size_t)(s * 4 + 1) * NC + c]
             + centp[(size_t)(s * 4 + 2) * NC + c] + centp[(size_t)(s * 4 + 3) * NC + c];
    cent[s * NC + c] = v * (1.0 / 256.0);
}

// ---- shared prologue: stage chunk + load 9 candidate centroids ------------
__device__ __forceinline__ void stage_and_scent(const float* __restrict__ x,
        const double* __restrict__ cent, int by, int bx, int g, int t,
        float* __restrict__ xb, double* __restrict__ scent) {
    int q = t >> 2, r = t & 3;
    const float* gp = x + (size_t)q * HWP + (size_t)(by * 16 + g * 4) * IMW + bx * 16 + r * 4;
    #pragma unroll
    for (int j = 0; j < 4; ++j) {
        float4 v = *(const float4*)(gp + (size_t)j * IMW);
        int p0 = j * 16 + r * 4;
        xb[(p0 + 0) * XROW + q] = v.x;
        xb[(p0 + 1) * XROW + q] = v.y;
        xb[(p0 + 2) * XROW + q] = v.z;
        xb[(p0 + 3) * XROW + q] = v.w;
    }
    for (int idx = t; idx < 9 * NC; idx += 256) {
        int k = idx >> 6, c = idx & 63;
        int cy = by + k / 3 - 1, cx = bx + k % 3 - 1;
        scent[idx] = (cy >= 0 && cy < NSH && cx >= 0 && cx < NSW)
                         ? cent[(cy * NSW + cx) * NC + c] : 0.0;
    }
}

// distance: thread (p = t>>2, cq = t&3), 16 channels each, quad shfl-reduce
__device__ __forceinline__ void chunk_dist(const float* __restrict__ xb,
        const double* __restrict__ scent, int p, int cq, double d[9]) {
    const float* xr = &xb[p * XROW + cq * 16];
    const double* sr = &scent[cq * 16];
    for (int i = 0; i < 16; ++i) {
        double v = (double)xr[i];
        #pragma unroll
        for (int k = 0; k < 9; ++k) {
            double diff = v - sr[k * NC + i];
            d[k] = fma(diff, diff, d[k]);
        }
    }
    #pragma unroll
    for (int k = 0; k < 9; ++k) {
        d[k] += __shfl_xor(d[k], 1, 64);
        d[k] += __shfl_xor(d[k], 2, 64);
    }
}

// ---- K2: soft iter: affinity softmax + per-(chunk,k) partial sums ---------
__global__ __launch_bounds__(256, 6) void k_iter(const float* __restrict__ x,
        const double* __restrict__ cent,
        double* __restrict__ bnum4, double* __restrict__ bden4) {
    int bg = blockIdx.x, b = bg >> 2, g = bg & 3;
    int by = b / NSW, bx = b % NSW;
    int t = threadIdx.x;
    __shared__ float  xb[64 * XROW];     // 16896 B
    __shared__ double scent[9 * NC];     // 4608 B
    __shared__ double aff[9 * 64];       // 4608 B

    stage_and_scent(x, cent, by, bx, g, t, xb, scent);
    bool vld[9];
    #pragma unroll
    for (int k = 0; k < 9; ++k) {
        int cy = by + k / 3 - 1, cx = bx + k % 3 - 1;
        vld[k] = (cy >= 0) && (cy < NSH) && (cx >= 0) && (cx < NSW);
    }
    __syncthreads();

    int p = t >> 2, cq = t & 3;
    double d[9] = {0, 0, 0, 0, 0, 0, 0, 0, 0};
    chunk_dist(xb, scent, p, cq, d);

    if (cq == 0) {                        // softmax, 16 lanes/wave active
        double m = -1e300;
        #pragma unroll
        for (int k = 0; k < 9; ++k) if (vld[k]) m = fmax(m, -d[k]);
        double ssum = 0.0;
        #pragma unroll
        for (int k = 0; k < 9; ++k) {
            double ek = vld[k] ? exp(-d[k] - m) : 0.0;
            aff[k * 64 + p] = ek;
            ssum += ek;
        }
        double inv = 1.0 / ssum;
        #pragma unroll
        for (int k = 0; k < 9; ++k) aff[k * 64 + p] *= inv;
    }
    __syncthreads();

    // dot: thread (c = t&63, kg = wave); aff reads wave-uniform (broadcast)
    int c = t & 63, kg = t >> 6;
    double acc[3] = {0, 0, 0}, den[3] = {0, 0, 0};
    for (int pp = 0; pp < 64; ++pp) {
        double xv = (double)xb[pp * XROW + c];
        #pragma unroll
        for (int s2 = 0; s2 < 3; ++s2) {
            int k = kg + 4 * s2;
            if (k < 9) {
                double av = aff[k * 64 + pp];
                acc[s2] = fma(av, xv, acc[s2]);
                den[s2] += av;
            }
        }
    }
    #pragma unroll
    for (int s2 = 0; s2 < 3; ++s2) {
        int k = kg + 4 * s2;
        if (k < 9) {
            bnum4[((size_t)bg * 9 + k) * NC + c] = acc[s2];
            if (c == 0) bden4[(size_t)bg * 9 + k] = den[s2];
        }
    }
}

// ---- K3: centroid update: gather 9k x 4g partials -> cent -----------------
__global__ __launch_bounds__(64) void k_gather_cent(const double* __restrict__ bnum4,
                                                    const double* __restrict__ bden4,
                                                    double* __restrict__ cent) {
    int s = blockIdx.x, c = threadIdx.x;
    int sy = s / NSW, sx = s % NSW;
    double num = 0.0, den = 0.0;
    #pragma unroll
    for (int k = 0; k < 9; ++k) {
        int by2 = sy - (k / 3 - 1), bx2 = sx - (k % 3 - 1);
        if (by2 >= 0 && by2 < NSH && bx2 >= 0 && bx2 < NSW) {
            int b2 = by2 * NSW + bx2;
            #pragma unroll
            for (int g = 0; g < 4; ++g) {
                num += bnum4[((size_t)(b2 * 4 + g) * 9 + k) * NC + c];
                den += bden4[(size_t)(b2 * 4 + g) * 9 + k];
            }
        }
    }
    cent[s * NC + c] = num / (den + 1e-16);
}

// ---- K4: final: argmax labels + hard-label partial sums -------------------
__global__ __launch_bounds__(256, 6) void k_final(const float* __restrict__ x,
        const double* __restrict__ cent, int* __restrict__ labels,
        double* __restrict__ bnum4, double* __restrict__ bden4) {
    int bg = blockIdx.x, b = bg >> 2, g = bg & 3;
    int by = b / NSW, bx = b % NSW;
    int t = threadIdx.x;
    __shared__ float  xb[64 * XROW];
    __shared__ double scent[9 * NC];
    __shared__ int    bk[64];

    stage_and_scent(x, cent, by, bx, g, t, xb, scent);
    bool vld[9];
    #pragma unroll
    for (int k = 0; k < 9; ++k) {
        int cy = by + k / 3 - 1, cx = bx + k % 3 - 1;
        vld[k] = (cy >= 0) && (cy < NSH) && (cx >= 0) && (cx < NSW);
    }
    __syncthreads();

    int p = t >> 2, cq = t & 3;
    double d[9] = {0, 0, 0, 0, 0, 0, 0, 0, 0};
    chunk_dist(xb, scent, p, cq, d);

    if (cq == 0) {
        double bestd = 1e300; int bestk = 0;
        #pragma unroll
        for (int k = 0; k < 9; ++k)
            if (vld[k] && d[k] < bestd) { bestd = d[k]; bestk = k; }  // first wins
        bk[p] = bestk;
        int prow = p >> 4, pcol = p & 15;
        labels[(size_t)(by * 16 + g * 4 + prow) * IMW + bx * 16 + pcol] =
            (by + bestk / 3 - 1) * NSW + (bx + bestk % 3 - 1);
    }
    __syncthreads();

    int c = t & 63, kg = t >> 6;
    double acc[3] = {0, 0, 0};
    int cnt[3] = {0, 0, 0};
    for (int pp = 0; pp < 64; ++pp) {
        int bkp = bk[pp];                        // wave-uniform broadcast
        double xv = (double)xb[pp * XROW + c];
        #pragma unroll
        for (int s2 = 0; s2 < 3; ++s2) {
            int k = kg + 4 * s2;
            if (k < 9 && bkp == k) { acc[s2] += xv; cnt[s2]++; }
        }
    }
    #pragma unroll
    for (int s2 = 0; s2 < 3; ++s2) {
        int k = kg + 4 * s2;
        if (k < 9) {
            bnum4[((size_t)bg * 9 + k) * NC + c] = acc[s2];
            if (c == 0) bden4[(size_t)bg * 9 + k] = (double)cnt[s2];
        }
    }
}

// ---- K5: gather paint sums -> per-superpixel channel means (f32) ----------
__global__ __launch_bounds__(64) void k_means_(const double* __restrict__ bnum4,
                                               const double* __restrict__ bden4,
                                               float* __restrict__ means) {
    int s = blockIdx.x, c = threadIdx.x;
    int sy = s / NSW, sx = s % NSW;
    double num = 0.0, den = 0.0;
    #pragma unroll
    for (int k = 0; k < 9; ++k) {
        int by2 = sy - (k / 3 - 1), bx2 = sx - (k % 3 - 1);
        if (by2 >= 0 && by2 < NSH && bx2 >= 0 && bx2 < NSW) {
            int b2 = by2 * NSW + bx2;
            #pragma unroll
            for (int g = 0; g < 4; ++g) {
                num += bnum4[((size_t)(b2 * 4 + g) * 9 + k) * NC + c];
                den += bden4[(size_t)(b2 * 4 + g) * 9 + k];
            }
        }
    }
    means[s * NC + c] = (float)(num / fmax(den, 1.0));
}

// ---- K6: paint out[c][p] = means[lab[p]][c]; 4 px x 4 ch per thread -------
__global__ __launch_bounds__(256) void k_paint(const int* __restrict__ labels,
                                               const float* __restrict__ means,
                                               float* __restrict__ out) {
    int p0 = (blockIdx.x * 256 + threadIdx.x) * 4;
    int4 lb = *(const int4*)&labels[p0];
    int c0 = blockIdx.y * 4;
    #pragma unroll
    for (int j = 0; j < 4; ++j) {
        int c = c0 + j;
        float4 o;
        o.x = means[lb.x * NC + c];
        o.y = means[lb.y * NC + c];
        o.z = means[lb.z * NC + c];
        o.w = means[lb.w * NC + c];
        *(float4*)&out[(size_t)c * HWP + p0] = o;
    }
}

extern "C" void kernel_launch(void* const* d_in, const int* in_sizes, int n_in,
                              void* d_out, int out_size, void* d_ws, size_t ws_size,
                              hipStream_t stream) {
    const float* x = (const float*)d_in[0];
    float* out = (float*)d_out;
    char* ws = (char*)d_ws;
    char* od = (char*)d_out;

    constexpr size_t CENTP_B = (size_t)NBG * NC * 8;      // 1179648
    constexpr size_t CENT_B  = (size_t)NS * NC * 8;       // 294912 (x2)
    constexpr size_t BNUM_B  = (size_t)NBG * 9 * NC * 8;  // 10616832
    constexpr size_t BDEN_B  = (size_t)NBG * 9 * 8;       // 165888
    constexpr size_t LAB_B   = (size_t)HWP * 4;           // 589824
    constexpr size_t MEANS_B = (size_t)NS * NC * 4;       // 147456
    constexpr size_t T_PAINT = LAB_B + MEANS_B;           // must live in ws
    constexpr size_t T_CENT  = T_PAINT + 2 * CENT_B;
    constexpr size_t T_ALL   = T_CENT + CENTP_B + BNUM_B + BDEN_B;

    int* labels = (int*)ws;
    float* means = (float*)(ws + LAB_B);
    double *centA, *centB, *centp, *bnum4, *bden4;
    if (ws_size >= T_ALL) {                    // everything in ws (~13.6 MB)
        centA = (double*)(ws + T_PAINT);
        centB = (double*)(ws + T_PAINT + CENT_B);
        centp = (double*)(ws + T_CENT);
        bnum4 = (double*)(ws + T_CENT + CENTP_B);
        bden4 = (double*)(ws + T_CENT + CENTP_B + BNUM_B);
    } else if (ws_size >= T_CENT) {            // big partials in d_out front
        centA = (double*)(ws + T_PAINT);
        centB = (double*)(ws + T_PAINT + CENT_B);
        centp = (double*)od;
        bnum4 = (double*)(od + CENTP_B);
        bden4 = (double*)(od + CENTP_B + BNUM_B);
    } else {                                   // only paint inputs in ws
        centp = (double*)od;
        bnum4 = (double*)(od + CENTP_B);
        bden4 = (double*)(od + CENTP_B + BNUM_B);
        centA = (double*)(od + CENTP_B + BNUM_B + BDEN_B);
        centB = (double*)(od + CENTP_B + BNUM_B + BDEN_B + CENT_B);
    }
    // d_out regions are all consumed before k_paint fully overwrites d_out.

    k_cent_part<<<NBG, 256, 0, stream>>>(x, centp);
    k_cent_red<<<NS, 64, 0, stream>>>(centp, centA);
    k_iter<<<NBG, 256, 0, stream>>>(x, centA, bnum4, bden4);
    k_gather_cent<<<NS, 64, 0, stream>>>(bnum4, bden4, centB);
    k_iter<<<NBG, 256, 0, stream>>>(x, centB, bnum4, bden4);
    k_gather_cent<<<NS, 64, 0, stream>>>(bnum4, bden4, centA);
    k_final<<<NBG, 256, 0, stream>>>(x, centA, labels, bnum4, bden4);
    k_means_<<<NS, 64, 0, stream>>>(bnum4, bden4, means);
    k_paint<<<dim3(HWP / 1024, NC / 4), 256, 0, stream>>>(labels, means, out);
}